// Round 2
// baseline (369.768 us; speedup 1.0000x reference)
//
#include <hip/hip_runtime.h>
#include <stdint.h>

#define HIDDEN 1024
#define BATCH  4
#define SEQ    2048
#define TOKENS (BATCH * SEQ)      // 8192
#define QKVD   (3 * HIDDEN)       // 3072

typedef unsigned short u16;
typedef __attribute__((ext_vector_type(8))) short   short8;   // 8 bf16 = 4 VGPRs
typedef __attribute__((ext_vector_type(4))) float   floatx4;

// deterministic round-to-nearest-even f32 -> bf16 (no NaN inputs here)
__device__ __forceinline__ u16 f32_bf16_rne(float f) {
    unsigned int u = __float_as_uint(f);
    u += 0x7FFFu + ((u >> 16) & 1u);
    return (u16)(u >> 16);
}

// ---------------------------------------------------------------- convert
__global__ __launch_bounds__(256) void cvt_bf16_kernel(
        const float* __restrict__ src, u16* __restrict__ dst, int n4) {
    int i = blockIdx.x * 256 + threadIdx.x;
    if (i >= n4) return;
    float4 v = ((const float4*)src)[i];
    ushort4 o;
    o.x = f32_bf16_rne(v.x); o.y = f32_bf16_rne(v.y);
    o.z = f32_bf16_rne(v.z); o.w = f32_bf16_rne(v.w);
    ((ushort4*)dst)[i] = o;
}

// ---------------------------------------------------------------- GEMM (NT)
// C[M,N] = A[M,K] * B[N,K]^T.  128x128 block tile, BK=32, 256 threads (4 waves),
// each wave 64x64 via 4x4 grid of 16x16x32 bf16 MFMA. global_load_lds width 16.
//
// LDS layout is chosen so fragment reads are LINEAR across the wave (zero bank
// conflicts): staging lane i loads tile element (row = chunk*16 + (i&15),
// kcol = (i>>4)*8), which global_load_lds places at chunkbase + i*16B. The MFMA
// A/B fragment for lane L is (row = chunk*16 + (L&15), k = (L>>4)*8) — i.e.
// exactly chunkbase + L*16B. Round 1 (row-major LDS) had 4 extra conflict
// cycles per ds_read_b128 (6.29M SQ_LDS_BANK_CONFLICT/dispatch).
//
// EPI: 0 = bf16 store + bias[col]; 1 = f32 store * scale; 2 = f32 store.
template <int EPI>
__global__ __launch_bounds__(256) void gemm_bt(
        const u16* __restrict__ A, const u16* __restrict__ B,
        void* __restrict__ Cv, const float* __restrict__ bias,
        int K, int lda, int ldb, int ldc,
        size_t sA, size_t sB, size_t sC, float scale) {
    __shared__ u16 As[128 * 32];   // 8 KB: 8 chunks of (16 rows x 32 k), lane-linear
    __shared__ u16 Bs[128 * 32];

    const int t    = threadIdx.x;
    const int lane = t & 63;
    const int wid  = t >> 6;
    const int bm   = blockIdx.y * 128;
    const int bn   = blockIdx.x * 128;

    const u16* Ab = A + (size_t)blockIdx.z * sA;
    const u16* Bb = B + (size_t)blockIdx.z * sB;

    // staging geometry: lane i -> row chunk*16 + (i&15), k-cols (i>>4)*8 .. +8
    const int srow = lane & 15;
    const int scol = (lane >> 4) * 8;

    // fragment geometry (verified m89/m91 mappings)
    const int wm = (wid >> 1) * 64;
    const int wn = (wid & 1) * 64;
    const int fr = lane & 15;            // row-in-16 of A/B fragment

    floatx4 acc[4][4];
#pragma unroll
    for (int i = 0; i < 4; i++)
#pragma unroll
        for (int j = 0; j < 4; j++) acc[i][j] = (floatx4){0.f, 0.f, 0.f, 0.f};

    for (int k0 = 0; k0 < K; k0 += 32) {
        __syncthreads();   // previous iter's LDS reads complete before overwrite
#pragma unroll
        for (int j = 0; j < 2; j++) {
            const int chunk = wid * 2 + j;                      // 0..7
            const int rt = chunk * 16 + srow;                   // tile row 0..127
            const u16* ga = Ab + (size_t)(bm + rt) * lda + (k0 + scol);
            __builtin_amdgcn_global_load_lds(
                (const __attribute__((address_space(1))) void*)ga,
                (__attribute__((address_space(3))) void*)(&As[chunk * 512]),
                16, 0, 0);
            const u16* gb = Bb + (size_t)(bn + rt) * ldb + (k0 + scol);
            __builtin_amdgcn_global_load_lds(
                (const __attribute__((address_space(1))) void*)gb,
                (__attribute__((address_space(3))) void*)(&Bs[chunk * 512]),
                16, 0, 0);
        }
        __syncthreads();   // compiler drains vmcnt before barrier

        short8 af[4], bf[4];
#pragma unroll
        for (int mi = 0; mi < 4; mi++)
            af[mi] = *(const short8*)&As[((wm >> 4) + mi) * 512 + lane * 8];
#pragma unroll
        for (int ni = 0; ni < 4; ni++)
            bf[ni] = *(const short8*)&Bs[((wn >> 4) + ni) * 512 + lane * 8];
#pragma unroll
        for (int mi = 0; mi < 4; mi++)
#pragma unroll
            for (int ni = 0; ni < 4; ni++)
                acc[mi][ni] = __builtin_amdgcn_mfma_f32_16x16x32_bf16(
                    af[mi], bf[ni], acc[mi][ni], 0, 0, 0);
    }

    // epilogue: C/D 16x16 mapping col=lane&15, row=(lane>>4)*4+reg
    const int crow0 = bm + wm + (lane >> 4) * 4;
    const int ccol0 = bn + wn + fr;
    const size_t coff = (size_t)blockIdx.z * sC;

    if (EPI == 0) {
        u16* C = (u16*)Cv;
        float bv[4];
#pragma unroll
        for (int ni = 0; ni < 4; ni++) bv[ni] = bias[ccol0 + ni * 16];
#pragma unroll
        for (int mi = 0; mi < 4; mi++)
#pragma unroll
            for (int ni = 0; ni < 4; ni++)
#pragma unroll
                for (int r = 0; r < 4; r++)
                    C[coff + (size_t)(crow0 + mi * 16 + r) * ldc + (ccol0 + ni * 16)] =
                        f32_bf16_rne(acc[mi][ni][r] + bv[ni]);
    } else {
        float* C = (float*)Cv;
#pragma unroll
        for (int mi = 0; mi < 4; mi++)
#pragma unroll
            for (int ni = 0; ni < 4; ni++)
#pragma unroll
                for (int r = 0; r < 4; r++) {
                    float v = acc[mi][ni][r];
                    if (EPI == 1) v *= scale;
                    C[coff + (size_t)(crow0 + mi * 16 + r) * ldc + (ccol0 + ni * 16)] = v;
                }
    }
}

// ---------------------------------------------------------------- softmax
// one block per row; 2048 fp32 scores (already scaled) -> 2048 bf16 probs
__global__ __launch_bounds__(256) void softmax_kernel(
        const float* __restrict__ S, u16* __restrict__ P) {
    __shared__ float redm[4];
    __shared__ float reds[4];
    const size_t base = (size_t)blockIdx.x * SEQ;
    const int t = threadIdx.x, lane = t & 63, wid = t >> 6;
    const float4* src = (const float4*)(S + base);
    float4 a = src[t], b = src[t + 256];

    float m = fmaxf(fmaxf(fmaxf(a.x, a.y), fmaxf(a.z, a.w)),
                    fmaxf(fmaxf(b.x, b.y), fmaxf(b.z, b.w)));
#pragma unroll
    for (int off = 32; off; off >>= 1) m = fmaxf(m, __shfl_xor(m, off, 64));
    if (lane == 0) redm[wid] = m;
    __syncthreads();
    m = fmaxf(fmaxf(redm[0], redm[1]), fmaxf(redm[2], redm[3]));

    float e[8];
    e[0] = __expf(a.x - m); e[1] = __expf(a.y - m);
    e[2] = __expf(a.z - m); e[3] = __expf(a.w - m);
    e[4] = __expf(b.x - m); e[5] = __expf(b.y - m);
    e[6] = __expf(b.z - m); e[7] = __expf(b.w - m);
    float s = e[0] + e[1] + e[2] + e[3] + e[4] + e[5] + e[6] + e[7];
#pragma unroll
    for (int off = 32; off; off >>= 1) s += __shfl_xor(s, off, 64);
    if (lane == 0) reds[wid] = s;
    __syncthreads();
    s = reds[0] + reds[1] + reds[2] + reds[3];
    const float r = 1.f / s;

    ushort4* dst = (ushort4*)(P + base);
    ushort4 o0, o1;
    o0.x = f32_bf16_rne(e[0] * r); o0.y = f32_bf16_rne(e[1] * r);
    o0.z = f32_bf16_rne(e[2] * r); o0.w = f32_bf16_rne(e[3] * r);
    o1.x = f32_bf16_rne(e[4] * r); o1.y = f32_bf16_rne(e[5] * r);
    o1.z = f32_bf16_rne(e[6] * r); o1.w = f32_bf16_rne(e[7] * r);
    dst[t] = o0;
    dst[t + 256] = o1;
}

// ---------------------------------------------------------------- V transpose
// Vt[b][h][s] <- qkv[b*SEQ+s][2*HIDDEN+h], 64x64 LDS tiles, pad 66 (bank-safe)
__global__ __launch_bounds__(256) void transposeV_kernel(
        const u16* __restrict__ qkv, u16* __restrict__ Vt) {
    __shared__ u16 tile[64][66];
    const int b = blockIdx.z;
    const int s0 = blockIdx.x * 64, h0 = blockIdx.y * 64;
    const int t = threadIdx.x;
    const int c = t & 63, r4 = t >> 6;
#pragma unroll
    for (int i = 0; i < 16; i++) {
        int sl = i * 4 + r4;
        tile[sl][c] = qkv[(size_t)(b * SEQ + s0 + sl) * QKVD + 2 * HIDDEN + h0 + c];
    }
    __syncthreads();
#pragma unroll
    for (int i = 0; i < 16; i++) {
        int hl = i * 4 + r4;
        Vt[(size_t)(b * HIDDEN + h0 + hl) * SEQ + s0 + c] = tile[c][hl];
    }
}

// ---------------------------------------------------------------- launch
extern "C" void kernel_launch(void* const* d_in, const int* in_sizes, int n_in,
                              void* d_out, int out_size, void* d_ws, size_t ws_size,
                              hipStream_t stream) {
    const float* x    = (const float*)d_in[0];   // [4,2048,1024]
    const float* W    = (const float*)d_in[1];   // [3072,1024]
    const float* bias = (const float*)d_in[2];   // [3072]
    float* out = (float*)d_out;                  // [4,2048,1024]

    // workspace layout (191 MB total)
    u16* Xb  = (u16*)d_ws;                                  // 8192x1024 bf16
    u16* Wb  = Xb + (size_t)TOKENS * HIDDEN;                // 3072x1024 bf16
    u16* qkv = Wb + (size_t)QKVD * HIDDEN;                  // 8192x3072 bf16
    float* scores = (float*)(qkv + (size_t)TOKENS * QKVD);  // 4x2048x2048 f32
    u16* P  = (u16*)(scores + (size_t)BATCH * SEQ * SEQ);   // 4x2048x2048 bf16
    u16* Vt = P + (size_t)BATCH * SEQ * SEQ;                // 4x1024x2048 bf16

    // 1) fp32 -> bf16 casts
    cvt_bf16_kernel<<<TOKENS * HIDDEN / 4 / 256, 256, 0, stream>>>(x, Xb, TOKENS * HIDDEN / 4);
    cvt_bf16_kernel<<<QKVD * HIDDEN / 4 / 256, 256, 0, stream>>>(W, Wb, QKVD * HIDDEN / 4);

    // 2) QKV projection: qkv = Xb @ Wb^T + bias  (bf16 out)
    gemm_bt<0><<<dim3(QKVD / 128, TOKENS / 128, 1), 256, 0, stream>>>(
        Xb, Wb, qkv, bias, HIDDEN, HIDDEN, HIDDEN, QKVD, 0, 0, 0, 1.f);

    // 3) scores = scale * Q @ K^T per batch (f32 out)
    gemm_bt<1><<<dim3(SEQ / 128, SEQ / 128, BATCH), 256, 0, stream>>>(
        qkv, qkv + HIDDEN, scores, nullptr, HIDDEN, QKVD, QKVD, SEQ,
        (size_t)SEQ * QKVD, (size_t)SEQ * QKVD, (size_t)SEQ * SEQ, 0.03125f);

    // 4) row softmax -> bf16 P
    softmax_kernel<<<BATCH * SEQ, 256, 0, stream>>>(scores, P);

    // 5) V transpose (bias already folded in step 2)
    transposeV_kernel<<<dim3(SEQ / 64, HIDDEN / 64, BATCH), 256, 0, stream>>>(qkv, Vt);

    // 6) out = P @ Vt^T per batch (f32 out)
    gemm_bt<2><<<dim3(HIDDEN / 128, SEQ / 128, BATCH), 256, 0, stream>>>(
        P, Vt, out, nullptr, SEQ, SEQ, SEQ, HIDDEN,
        (size_t)SEQ * SEQ, (size_t)HIDDEN * SEQ, (size_t)SEQ * HIDDEN, 1.f);
}

// Round 3
// 308.171 us; speedup vs baseline: 1.1999x; 1.1999x over previous
//
#include <hip/hip_runtime.h>
#include <stdint.h>

#define HIDDEN 1024
#define BATCH  4
#define SEQ    2048
#define TOKENS (BATCH * SEQ)      // 8192
#define QKVD   (3 * HIDDEN)       // 3072

typedef unsigned short u16;
typedef __attribute__((ext_vector_type(8))) short   short8;   // 8 bf16 = 4 VGPRs
typedef __attribute__((ext_vector_type(4))) float   floatx4;

// deterministic round-to-nearest-even f32 -> bf16 (no NaN inputs here)
__device__ __forceinline__ u16 f32_bf16_rne(float f) {
    unsigned int u = __float_as_uint(f);
    u += 0x7FFFu + ((u >> 16) & 1u);
    return (u16)(u >> 16);
}

// ---------------------------------------------------------------- convert
__global__ __launch_bounds__(256) void cvt_bf16_kernel(
        const float* __restrict__ src, u16* __restrict__ dst, int n4) {
    int i = blockIdx.x * 256 + threadIdx.x;
    if (i >= n4) return;
    float4 v = ((const float4*)src)[i];
    ushort4 o;
    o.x = f32_bf16_rne(v.x); o.y = f32_bf16_rne(v.y);
    o.z = f32_bf16_rne(v.z); o.w = f32_bf16_rne(v.w);
    ((ushort4*)dst)[i] = o;
}

// ---------------------------------------------------------------- GEMM (NT)
// C[M,N] = A[M,K] * B[N,K]^T.  128x128 block tile, BK=32, 256 threads (4 waves),
// each wave 64x64 via 4x4 grid of 16x16x32 bf16 MFMA. global_load_lds width 16.
//
// Staging map (round 3): lane i -> row r=i>>2, 16B k-chunk c=(i&3)^((r>>1)&3).
//  * Global side: each 4-lane cluster covers one FULL contiguous 64-B row
//    segment (same address set as round 1 -> full coalescing; round 2's
//    16B-per-lane scatter dropped hbm_gbps 1540->1120).
//  * LDS side: induced layout addr(r,c) = r*64 + (c ^ ((r>>1)&3))*16, so the
//    MFMA fragment read (lane L: r=L&15, c=L>>4) spreads each 16-lane quarter
//    across all 8 bank-quads 2-way (free; round 1's row-major layout was
//    8-way on 2 quads -> 6.29M SQ_LDS_BANK_CONFLICT/dispatch).
//
// EPI: 0 = bf16 store + bias[col]; 1 = f32 store * scale; 2 = f32 store.
template <int EPI>
__global__ __launch_bounds__(256) void gemm_bt(
        const u16* __restrict__ A, const u16* __restrict__ B,
        void* __restrict__ Cv, const float* __restrict__ bias,
        int K, int lda, int ldb, int ldc,
        size_t sA, size_t sB, size_t sC, float scale) {
    __shared__ u16 As[128 * 32];   // 8 KB: 8 chunks of (16 rows x 32 k), swizzled
    __shared__ u16 Bs[128 * 32];

    const int t    = threadIdx.x;
    const int lane = t & 63;
    const int wid  = t >> 6;
    const int bm   = blockIdx.y * 128;
    const int bn   = blockIdx.x * 128;

    const u16* Ab = A + (size_t)blockIdx.z * sA;
    const u16* Bb = B + (size_t)blockIdx.z * sB;

    // staging geometry: lane i -> row i>>2, k-chunk (i&3)^((i>>3)&3)
    const int srow = lane >> 2;                          // 0..15
    const int scol = ((lane & 3) ^ ((lane >> 3) & 3)) * 8;

    // fragment geometry (verified m89/m91 mappings)
    const int wm = (wid >> 1) * 64;
    const int wn = (wid & 1) * 64;
    const int fr = lane & 15;            // row-in-16 of A/B fragment
    const int fc = lane >> 4;            // k-chunk 0..3 of fragment
    // LDS element offset of (row=fr, chunk=fc) within a 16-row chunk:
    const int foff = fr * 32 + ((fc ^ ((fr >> 1) & 3)) * 8);

    floatx4 acc[4][4];
#pragma unroll
    for (int i = 0; i < 4; i++)
#pragma unroll
        for (int j = 0; j < 4; j++) acc[i][j] = (floatx4){0.f, 0.f, 0.f, 0.f};

    for (int k0 = 0; k0 < K; k0 += 32) {
        __syncthreads();   // previous iter's LDS reads complete before overwrite
#pragma unroll
        for (int j = 0; j < 2; j++) {
            const int chunk = wid * 2 + j;                      // 0..7
            const int rt = chunk * 16 + srow;                   // tile row 0..127
            const u16* ga = Ab + (size_t)(bm + rt) * lda + (k0 + scol);
            __builtin_amdgcn_global_load_lds(
                (const __attribute__((address_space(1))) void*)ga,
                (__attribute__((address_space(3))) void*)(&As[chunk * 512]),
                16, 0, 0);
            const u16* gb = Bb + (size_t)(bn + rt) * ldb + (k0 + scol);
            __builtin_amdgcn_global_load_lds(
                (const __attribute__((address_space(1))) void*)gb,
                (__attribute__((address_space(3))) void*)(&Bs[chunk * 512]),
                16, 0, 0);
        }
        __syncthreads();   // compiler drains vmcnt before barrier

        short8 af[4], bf[4];
#pragma unroll
        for (int mi = 0; mi < 4; mi++)
            af[mi] = *(const short8*)&As[((wm >> 4) + mi) * 512 + foff];
#pragma unroll
        for (int ni = 0; ni < 4; ni++)
            bf[ni] = *(const short8*)&Bs[((wn >> 4) + ni) * 512 + foff];
#pragma unroll
        for (int mi = 0; mi < 4; mi++)
#pragma unroll
            for (int ni = 0; ni < 4; ni++)
                acc[mi][ni] = __builtin_amdgcn_mfma_f32_16x16x32_bf16(
                    af[mi], bf[ni], acc[mi][ni], 0, 0, 0);
    }

    // epilogue: C/D 16x16 mapping col=lane&15, row=(lane>>4)*4+reg
    const int crow0 = bm + wm + (lane >> 4) * 4;
    const int ccol0 = bn + wn + fr;
    const size_t coff = (size_t)blockIdx.z * sC;

    if (EPI == 0) {
        u16* C = (u16*)Cv;
        float bv[4];
#pragma unroll
        for (int ni = 0; ni < 4; ni++) bv[ni] = bias[ccol0 + ni * 16];
#pragma unroll
        for (int mi = 0; mi < 4; mi++)
#pragma unroll
            for (int ni = 0; ni < 4; ni++)
#pragma unroll
                for (int r = 0; r < 4; r++)
                    C[coff + (size_t)(crow0 + mi * 16 + r) * ldc + (ccol0 + ni * 16)] =
                        f32_bf16_rne(acc[mi][ni][r] + bv[ni]);
    } else {
        float* C = (float*)Cv;
#pragma unroll
        for (int mi = 0; mi < 4; mi++)
#pragma unroll
            for (int ni = 0; ni < 4; ni++)
#pragma unroll
                for (int r = 0; r < 4; r++) {
                    float v = acc[mi][ni][r];
                    if (EPI == 1) v *= scale;
                    C[coff + (size_t)(crow0 + mi * 16 + r) * ldc + (ccol0 + ni * 16)] = v;
                }
    }
}

// ---------------------------------------------------------------- softmax
// one block per row; 2048 fp32 scores (already scaled) -> 2048 bf16 probs
__global__ __launch_bounds__(256) void softmax_kernel(
        const float* __restrict__ S, u16* __restrict__ P) {
    __shared__ float redm[4];
    __shared__ float reds[4];
    const size_t base = (size_t)blockIdx.x * SEQ;
    const int t = threadIdx.x, lane = t & 63, wid = t >> 6;
    const float4* src = (const float4*)(S + base);
    float4 a = src[t], b = src[t + 256];

    float m = fmaxf(fmaxf(fmaxf(a.x, a.y), fmaxf(a.z, a.w)),
                    fmaxf(fmaxf(b.x, b.y), fmaxf(b.z, b.w)));
#pragma unroll
    for (int off = 32; off; off >>= 1) m = fmaxf(m, __shfl_xor(m, off, 64));
    if (lane == 0) redm[wid] = m;
    __syncthreads();
    m = fmaxf(fmaxf(redm[0], redm[1]), fmaxf(redm[2], redm[3]));

    float e[8];
    e[0] = __expf(a.x - m); e[1] = __expf(a.y - m);
    e[2] = __expf(a.z - m); e[3] = __expf(a.w - m);
    e[4] = __expf(b.x - m); e[5] = __expf(b.y - m);
    e[6] = __expf(b.z - m); e[7] = __expf(b.w - m);
    float s = e[0] + e[1] + e[2] + e[3] + e[4] + e[5] + e[6] + e[7];
#pragma unroll
    for (int off = 32; off; off >>= 1) s += __shfl_xor(s, off, 64);
    if (lane == 0) reds[wid] = s;
    __syncthreads();
    s = reds[0] + reds[1] + reds[2] + reds[3];
    const float r = 1.f / s;

    ushort4* dst = (ushort4*)(P + base);
    ushort4 o0, o1;
    o0.x = f32_bf16_rne(e[0] * r); o0.y = f32_bf16_rne(e[1] * r);
    o0.z = f32_bf16_rne(e[2] * r); o0.w = f32_bf16_rne(e[3] * r);
    o1.x = f32_bf16_rne(e[4] * r); o1.y = f32_bf16_rne(e[5] * r);
    o1.z = f32_bf16_rne(e[6] * r); o1.w = f32_bf16_rne(e[7] * r);
    dst[t] = o0;
    dst[t + 256] = o1;
}

// ---------------------------------------------------------------- V transpose
// Vt[b][h][s] <- qkv[b*SEQ+s][2*HIDDEN+h], 64x64 LDS tiles, pad 66 (bank-safe)
__global__ __launch_bounds__(256) void transposeV_kernel(
        const u16* __restrict__ qkv, u16* __restrict__ Vt) {
    __shared__ u16 tile[64][66];
    const int b = blockIdx.z;
    const int s0 = blockIdx.x * 64, h0 = blockIdx.y * 64;
    const int t = threadIdx.x;
    const int c = t & 63, r4 = t >> 6;
#pragma unroll
    for (int i = 0; i < 16; i++) {
        int sl = i * 4 + r4;
        tile[sl][c] = qkv[(size_t)(b * SEQ + s0 + sl) * QKVD + 2 * HIDDEN + h0 + c];
    }
    __syncthreads();
#pragma unroll
    for (int i = 0; i < 16; i++) {
        int hl = i * 4 + r4;
        Vt[(size_t)(b * HIDDEN + h0 + hl) * SEQ + s0 + c] = tile[c][hl];
    }
}

// ---------------------------------------------------------------- launch
extern "C" void kernel_launch(void* const* d_in, const int* in_sizes, int n_in,
                              void* d_out, int out_size, void* d_ws, size_t ws_size,
                              hipStream_t stream) {
    const float* x    = (const float*)d_in[0];   // [4,2048,1024]
    const float* W    = (const float*)d_in[1];   // [3072,1024]
    const float* bias = (const float*)d_in[2];   // [3072]
    float* out = (float*)d_out;                  // [4,2048,1024]

    // workspace layout (191 MB total)
    u16* Xb  = (u16*)d_ws;                                  // 8192x1024 bf16
    u16* Wb  = Xb + (size_t)TOKENS * HIDDEN;                // 3072x1024 bf16
    u16* qkv = Wb + (size_t)QKVD * HIDDEN;                  // 8192x3072 bf16
    float* scores = (float*)(qkv + (size_t)TOKENS * QKVD);  // 4x2048x2048 f32
    u16* P  = (u16*)(scores + (size_t)BATCH * SEQ * SEQ);   // 4x2048x2048 bf16
    u16* Vt = P + (size_t)BATCH * SEQ * SEQ;                // 4x1024x2048 bf16

    // 1) fp32 -> bf16 casts
    cvt_bf16_kernel<<<TOKENS * HIDDEN / 4 / 256, 256, 0, stream>>>(x, Xb, TOKENS * HIDDEN / 4);
    cvt_bf16_kernel<<<QKVD * HIDDEN / 4 / 256, 256, 0, stream>>>(W, Wb, QKVD * HIDDEN / 4);

    // 2) QKV projection: qkv = Xb @ Wb^T + bias  (bf16 out)
    gemm_bt<0><<<dim3(QKVD / 128, TOKENS / 128, 1), 256, 0, stream>>>(
        Xb, Wb, qkv, bias, HIDDEN, HIDDEN, HIDDEN, QKVD, 0, 0, 0, 1.f);

    // 3) scores = scale * Q @ K^T per batch (f32 out)
    gemm_bt<1><<<dim3(SEQ / 128, SEQ / 128, BATCH), 256, 0, stream>>>(
        qkv, qkv + HIDDEN, scores, nullptr, HIDDEN, QKVD, QKVD, SEQ,
        (size_t)SEQ * QKVD, (size_t)SEQ * QKVD, (size_t)SEQ * SEQ, 0.03125f);

    // 4) row softmax -> bf16 P
    softmax_kernel<<<BATCH * SEQ, 256, 0, stream>>>(scores, P);

    // 5) V transpose (bias already folded in step 2)
    transposeV_kernel<<<dim3(SEQ / 64, HIDDEN / 64, BATCH), 256, 0, stream>>>(qkv, Vt);

    // 6) out = P @ Vt^T per batch (f32 out)
    gemm_bt<2><<<dim3(HIDDEN / 128, SEQ / 128, BATCH), 256, 0, stream>>>(
        P, Vt, out, nullptr, SEQ, SEQ, SEQ, HIDDEN,
        (size_t)SEQ * SEQ, (size_t)HIDDEN * SEQ, (size_t)SEQ * HIDDEN, 1.f);
}

// Round 4
// 299.659 us; speedup vs baseline: 1.2340x; 1.0284x over previous
//
#include <hip/hip_runtime.h>
#include <stdint.h>

#define HIDDEN 1024
#define BATCH  4
#define SEQ    2048
#define TOKENS (BATCH * SEQ)      // 8192
#define QKVD   (3 * HIDDEN)       // 3072

typedef unsigned short u16;
typedef __attribute__((ext_vector_type(8))) short   short8;   // 8 bf16 = 4 VGPRs
typedef __attribute__((ext_vector_type(4))) float   floatx4;

// deterministic round-to-nearest-even f32 -> bf16 (no NaN inputs here)
__device__ __forceinline__ u16 f32_bf16_rne(float f) {
    unsigned int u = __float_as_uint(f);
    u += 0x7FFFu + ((u >> 16) & 1u);
    return (u16)(u >> 16);
}

// ---------------------------------------------------------------- convert
__global__ __launch_bounds__(256) void cvt_bf16_kernel(
        const float* __restrict__ src, u16* __restrict__ dst, int n4) {
    int i = blockIdx.x * 256 + threadIdx.x;
    if (i >= n4) return;
    float4 v = ((const float4*)src)[i];
    ushort4 o;
    o.x = f32_bf16_rne(v.x); o.y = f32_bf16_rne(v.y);
    o.z = f32_bf16_rne(v.z); o.w = f32_bf16_rne(v.w);
    ((ushort4*)dst)[i] = o;
}

// ---------------------------------------------------------------- GEMM (NT)
// C[M,N] = A[M,K] * B[N,K]^T.  128x128 block tile, BK=64, 256 threads (4 waves),
// each wave 64x64 via 4x4 grid of 16x16x32 bf16 MFMA. global_load_lds width 16.
//
// Round 3 diagnosis: no pipe saturated (Mfma 26%, VALU 45%, HBM 19%) -> the
// limiter is the per-k-iter s_waitcnt vmcnt(0)+s_barrier drain with only ~2-3
// blocks/CU resident. Round 4: BK=64 halves the number of drains (same
// bytes, same MFMA count, half the barriers). LDS 32 KB -> 5 blocks/CU cap,
// above actual residency.
//
// Staging map per 64-B half-row (verified round 3: full coalescing + zero
// LDS bank conflicts): lane i -> row r=i>>2, 16B chunk c=(i&3)^((r>>1)&3);
// HW stores lane i at ldsbase+i*16, so LDS slot p of row r holds global
// chunk p^((r>>1)&3); fragment read addr = fr*32 + ((fc^((fr>>1)&3))*8).
//
// EPI: 0 = bf16 store + bias[col]; 1 = f32 store * scale; 2 = f32 store.
template <int EPI>
__global__ __launch_bounds__(256) void gemm_bt(
        const u16* __restrict__ A, const u16* __restrict__ B,
        void* __restrict__ Cv, const float* __restrict__ bias,
        int K, int lda, int ldb, int ldc,
        size_t sA, size_t sB, size_t sC, float scale) {
    __shared__ u16 As[128 * 64];   // 16 KB: 8 rowchunks x (2 k-halves x 512 elem)
    __shared__ u16 Bs[128 * 64];

    const int t    = threadIdx.x;
    const int lane = t & 63;
    const int wid  = t >> 6;
    const int bm   = blockIdx.y * 128;
    const int bn   = blockIdx.x * 128;

    const u16* Ab = A + (size_t)blockIdx.z * sA;
    const u16* Bb = B + (size_t)blockIdx.z * sB;

    // staging geometry: lane i -> row i>>2, 16B chunk (i&3)^((i>>3)&3)
    const int srow = lane >> 2;                          // 0..15
    const int scol = ((lane & 3) ^ ((lane >> 3) & 3)) * 8;

    // fragment geometry (verified m89/m91 mappings)
    const int wm = (wid >> 1) * 64;
    const int wn = (wid & 1) * 64;
    const int fr = lane & 15;            // row-in-16 of A/B fragment
    const int fc = lane >> 4;            // 16B k-chunk 0..3 within a 64B half
    // LDS elem offset of (row=fr, chunk=fc) within a 512-elem (16 row) half:
    const int foff = fr * 32 + ((fc ^ ((fr >> 1) & 3)) * 8);

    floatx4 acc[4][4];
#pragma unroll
    for (int i = 0; i < 4; i++)
#pragma unroll
        for (int j = 0; j < 4; j++) acc[i][j] = (floatx4){0.f, 0.f, 0.f, 0.f};

    for (int k0 = 0; k0 < K; k0 += 64) {
        __syncthreads();   // previous iter's LDS reads complete before overwrite
#pragma unroll
        for (int j = 0; j < 2; j++) {
            const int chunk = wid * 2 + j;                      // 0..7
            const int rt = chunk * 16 + srow;                   // tile row 0..127
            const u16* garow = Ab + (size_t)(bm + rt) * lda + k0 + scol;
            const u16* gbrow = Bb + (size_t)(bn + rt) * ldb + k0 + scol;
#pragma unroll
            for (int h = 0; h < 2; h++) {
                __builtin_amdgcn_global_load_lds(
                    (const __attribute__((address_space(1))) void*)(garow + h * 32),
                    (__attribute__((address_space(3))) void*)(&As[chunk * 1024 + h * 512]),
                    16, 0, 0);
                __builtin_amdgcn_global_load_lds(
                    (const __attribute__((address_space(1))) void*)(gbrow + h * 32),
                    (__attribute__((address_space(3))) void*)(&Bs[chunk * 1024 + h * 512]),
                    16, 0, 0);
            }
        }
        __syncthreads();   // compiler drains vmcnt before barrier

#pragma unroll
        for (int s = 0; s < 2; s++) {
            const int fo = s * 512 + foff;
            short8 af[4], bf[4];
#pragma unroll
            for (int mi = 0; mi < 4; mi++)
                af[mi] = *(const short8*)&As[((wm >> 4) + mi) * 1024 + fo];
#pragma unroll
            for (int ni = 0; ni < 4; ni++)
                bf[ni] = *(const short8*)&Bs[((wn >> 4) + ni) * 1024 + fo];
#pragma unroll
            for (int mi = 0; mi < 4; mi++)
#pragma unroll
                for (int ni = 0; ni < 4; ni++)
                    acc[mi][ni] = __builtin_amdgcn_mfma_f32_16x16x32_bf16(
                        af[mi], bf[ni], acc[mi][ni], 0, 0, 0);
        }
    }

    // epilogue: C/D 16x16 mapping col=lane&15, row=(lane>>4)*4+reg
    const int crow0 = bm + wm + (lane >> 4) * 4;
    const int ccol0 = bn + wn + fr;
    const size_t coff = (size_t)blockIdx.z * sC;

    if (EPI == 0) {
        u16* C = (u16*)Cv;
        float bv[4];
#pragma unroll
        for (int ni = 0; ni < 4; ni++) bv[ni] = bias[ccol0 + ni * 16];
#pragma unroll
        for (int mi = 0; mi < 4; mi++)
#pragma unroll
            for (int ni = 0; ni < 4; ni++)
#pragma unroll
                for (int r = 0; r < 4; r++)
                    C[coff + (size_t)(crow0 + mi * 16 + r) * ldc + (ccol0 + ni * 16)] =
                        f32_bf16_rne(acc[mi][ni][r] + bv[ni]);
    } else {
        float* C = (float*)Cv;
#pragma unroll
        for (int mi = 0; mi < 4; mi++)
#pragma unroll
            for (int ni = 0; ni < 4; ni++)
#pragma unroll
                for (int r = 0; r < 4; r++) {
                    float v = acc[mi][ni][r];
                    if (EPI == 1) v *= scale;
                    C[coff + (size_t)(crow0 + mi * 16 + r) * ldc + (ccol0 + ni * 16)] = v;
                }
    }
}

// ---------------------------------------------------------------- softmax
// one block per row; 2048 fp32 scores (already scaled) -> 2048 bf16 probs
__global__ __launch_bounds__(256) void softmax_kernel(
        const float* __restrict__ S, u16* __restrict__ P) {
    __shared__ float redm[4];
    __shared__ float reds[4];
    const size_t base = (size_t)blockIdx.x * SEQ;
    const int t = threadIdx.x, lane = t & 63, wid = t >> 6;
    const float4* src = (const float4*)(S + base);
    float4 a = src[t], b = src[t + 256];

    float m = fmaxf(fmaxf(fmaxf(a.x, a.y), fmaxf(a.z, a.w)),
                    fmaxf(fmaxf(b.x, b.y), fmaxf(b.z, b.w)));
#pragma unroll
    for (int off = 32; off; off >>= 1) m = fmaxf(m, __shfl_xor(m, off, 64));
    if (lane == 0) redm[wid] = m;
    __syncthreads();
    m = fmaxf(fmaxf(redm[0], redm[1]), fmaxf(redm[2], redm[3]));

    float e[8];
    e[0] = __expf(a.x - m); e[1] = __expf(a.y - m);
    e[2] = __expf(a.z - m); e[3] = __expf(a.w - m);
    e[4] = __expf(b.x - m); e[5] = __expf(b.y - m);
    e[6] = __expf(b.z - m); e[7] = __expf(b.w - m);
    float s = e[0] + e[1] + e[2] + e[3] + e[4] + e[5] + e[6] + e[7];
#pragma unroll
    for (int off = 32; off; off >>= 1) s += __shfl_xor(s, off, 64);
    if (lane == 0) reds[wid] = s;
    __syncthreads();
    s = reds[0] + reds[1] + reds[2] + reds[3];
    const float r = 1.f / s;

    ushort4* dst = (ushort4*)(P + base);
    ushort4 o0, o1;
    o0.x = f32_bf16_rne(e[0] * r); o0.y = f32_bf16_rne(e[1] * r);
    o0.z = f32_bf16_rne(e[2] * r); o0.w = f32_bf16_rne(e[3] * r);
    o1.x = f32_bf16_rne(e[4] * r); o1.y = f32_bf16_rne(e[5] * r);
    o1.z = f32_bf16_rne(e[6] * r); o1.w = f32_bf16_rne(e[7] * r);
    dst[t] = o0;
    dst[t + 256] = o1;
}

// ---------------------------------------------------------------- V transpose
// Vt[b][h][s] <- qkv[b*SEQ+s][2*HIDDEN+h], 64x64 LDS tiles, pad 66 (bank-safe)
__global__ __launch_bounds__(256) void transposeV_kernel(
        const u16* __restrict__ qkv, u16* __restrict__ Vt) {
    __shared__ u16 tile[64][66];
    const int b = blockIdx.z;
    const int s0 = blockIdx.x * 64, h0 = blockIdx.y * 64;
    const int t = threadIdx.x;
    const int c = t & 63, r4 = t >> 6;
#pragma unroll
    for (int i = 0; i < 16; i++) {
        int sl = i * 4 + r4;
        tile[sl][c] = qkv[(size_t)(b * SEQ + s0 + sl) * QKVD + 2 * HIDDEN + h0 + c];
    }
    __syncthreads();
#pragma unroll
    for (int i = 0; i < 16; i++) {
        int hl = i * 4 + r4;
        Vt[(size_t)(b * HIDDEN + h0 + hl) * SEQ + s0 + c] = tile[c][hl];
    }
}

// ---------------------------------------------------------------- launch
extern "C" void kernel_launch(void* const* d_in, const int* in_sizes, int n_in,
                              void* d_out, int out_size, void* d_ws, size_t ws_size,
                              hipStream_t stream) {
    const float* x    = (const float*)d_in[0];   // [4,2048,1024]
    const float* W    = (const float*)d_in[1];   // [3072,1024]
    const float* bias = (const float*)d_in[2];   // [3072]
    float* out = (float*)d_out;                  // [4,2048,1024]

    // workspace layout (191 MB total)
    u16* Xb  = (u16*)d_ws;                                  // 8192x1024 bf16
    u16* Wb  = Xb + (size_t)TOKENS * HIDDEN;                // 3072x1024 bf16
    u16* qkv = Wb + (size_t)QKVD * HIDDEN;                  // 8192x3072 bf16
    float* scores = (float*)(qkv + (size_t)TOKENS * QKVD);  // 4x2048x2048 f32
    u16* P  = (u16*)(scores + (size_t)BATCH * SEQ * SEQ);   // 4x2048x2048 bf16
    u16* Vt = P + (size_t)BATCH * SEQ * SEQ;                // 4x1024x2048 bf16

    // 1) fp32 -> bf16 casts
    cvt_bf16_kernel<<<TOKENS * HIDDEN / 4 / 256, 256, 0, stream>>>(x, Xb, TOKENS * HIDDEN / 4);
    cvt_bf16_kernel<<<QKVD * HIDDEN / 4 / 256, 256, 0, stream>>>(W, Wb, QKVD * HIDDEN / 4);

    // 2) QKV projection: qkv = Xb @ Wb^T + bias  (bf16 out)
    gemm_bt<0><<<dim3(QKVD / 128, TOKENS / 128, 1), 256, 0, stream>>>(
        Xb, Wb, qkv, bias, HIDDEN, HIDDEN, HIDDEN, QKVD, 0, 0, 0, 1.f);

    // 3) scores = scale * Q @ K^T per batch (f32 out)
    gemm_bt<1><<<dim3(SEQ / 128, SEQ / 128, BATCH), 256, 0, stream>>>(
        qkv, qkv + HIDDEN, scores, nullptr, HIDDEN, QKVD, QKVD, SEQ,
        (size_t)SEQ * QKVD, (size_t)SEQ * QKVD, (size_t)SEQ * SEQ, 0.03125f);

    // 4) row softmax -> bf16 P
    softmax_kernel<<<BATCH * SEQ, 256, 0, stream>>>(scores, P);

    // 5) V transpose (bias already folded in step 2)
    transposeV_kernel<<<dim3(SEQ / 64, HIDDEN / 64, BATCH), 256, 0, stream>>>(qkv, Vt);

    // 6) out = P @ Vt^T per batch (f32 out)
    gemm_bt<2><<<dim3(HIDDEN / 128, SEQ / 128, BATCH), 256, 0, stream>>>(
        P, Vt, out, nullptr, SEQ, SEQ, SEQ, HIDDEN,
        (size_t)SEQ * SEQ, (size_t)HIDDEN * SEQ, (size_t)SEQ * HIDDEN, 1.f);
}

// Round 5
// 291.791 us; speedup vs baseline: 1.2672x; 1.0270x over previous
//
#include <hip/hip_runtime.h>
#include <stdint.h>

#define HIDDEN 1024
#define BATCH  4
#define SEQ    2048
#define TOKENS (BATCH * SEQ)      // 8192
#define QKVD   (3 * HIDDEN)       // 3072

typedef unsigned short u16;
typedef __attribute__((ext_vector_type(8))) short   short8;   // 8 bf16 = 4 VGPRs
typedef __attribute__((ext_vector_type(4))) float   floatx4;

// deterministic round-to-nearest-even f32 -> bf16 (no NaN inputs here)
__device__ __forceinline__ u16 f32_bf16_rne(float f) {
    unsigned int u = __float_as_uint(f);
    u += 0x7FFFu + ((u >> 16) & 1u);
    return (u16)(u >> 16);
}

// ---------------------------------------------------------------- convert
__global__ __launch_bounds__(256) void cvt_bf16_kernel(
        const float* __restrict__ src, u16* __restrict__ dst, int n4) {
    int i = blockIdx.x * 256 + threadIdx.x;
    if (i >= n4) return;
    float4 v = ((const float4*)src)[i];
    ushort4 o;
    o.x = f32_bf16_rne(v.x); o.y = f32_bf16_rne(v.y);
    o.z = f32_bf16_rne(v.z); o.w = f32_bf16_rne(v.w);
    ((ushort4*)dst)[i] = o;
}

// ---------------------------------------------------------------- GEMM (NT)
// C[M,N] = A[M,K] * B[N,K]^T.  128x128 block tile, BK=32 DOUBLE-BUFFERED,
// 256 threads (4 waves), each wave 64x64 via 4x4 grid of 16x16x32 bf16 MFMA.
//
// Round 4 post-mortem: 2-barrier K-loop exposes full load latency every iter
// (loads issued then immediately drained by vmcnt(0)+barrier; nothing in
// flight during compute). Rounds 1/3/4 all ~83us regardless of conflicts /
// coalescing / barrier count -> latency-bound. Round 5: double-buffer LDS,
// ONE barrier per iter; prefetch for iter k+1 is issued right after the
// barrier and drains at the NEXT barrier, i.e. a full compute phase later.
//
// Staging map per 64-B row segment (verified rounds 3-4: full coalescing +
// zero LDS bank conflicts): lane i -> row r=i>>2, 16B chunk c=(i&3)^((r>>1)&3);
// HW stores lane i at ldsbase+i*16; fragment read addr = fr*32+((fc^((fr>>1)&3))*8).
//
// EPI: 0 = bf16 store + bias[col]; 1 = f32 store * scale; 2 = f32 store.
template <int EPI>
__global__ __launch_bounds__(256) void gemm_bt(
        const u16* __restrict__ A, const u16* __restrict__ B,
        void* __restrict__ Cv, const float* __restrict__ bias,
        int K, int lda, int ldb, int ldc,
        size_t sA, size_t sB, size_t sC, float scale) {
    __shared__ u16 As[2][128 * 32];   // 2 x 8 KB
    __shared__ u16 Bs[2][128 * 32];

    const int t    = threadIdx.x;
    const int lane = t & 63;
    const int wid  = t >> 6;
    const int bm   = blockIdx.y * 128;
    const int bn   = blockIdx.x * 128;

    const u16* Ab = A + (size_t)blockIdx.z * sA;
    const u16* Bb = B + (size_t)blockIdx.z * sB;

    // staging geometry: lane i -> row i>>2, 16B chunk (i&3)^((i>>3)&3)
    const int srow = lane >> 2;                          // 0..15
    const int scol = ((lane & 3) ^ ((lane >> 3) & 3)) * 8;

    // fragment geometry (verified m89/m91 mappings)
    const int wm = (wid >> 1) * 64;
    const int wn = (wid & 1) * 64;
    const int fr = lane & 15;            // row-in-16 of A/B fragment
    const int fc = lane >> 4;            // 16B k-chunk 0..3
    const int foff = fr * 32 + ((fc ^ ((fr >> 1) & 3)) * 8);

    // per-wave staging rows (two 16-row chunks)
    const int c0 = wid * 2, c1 = wid * 2 + 1;
    const u16* gA0 = Ab + (size_t)(bm + c0 * 16 + srow) * lda + scol;
    const u16* gA1 = Ab + (size_t)(bm + c1 * 16 + srow) * lda + scol;
    const u16* gB0 = Bb + (size_t)(bn + c0 * 16 + srow) * ldb + scol;
    const u16* gB1 = Bb + (size_t)(bn + c1 * 16 + srow) * ldb + scol;

    auto stage = [&](int buf, int k0) {
        __builtin_amdgcn_global_load_lds(
            (const __attribute__((address_space(1))) void*)(gA0 + k0),
            (__attribute__((address_space(3))) void*)(&As[buf][c0 * 512]), 16, 0, 0);
        __builtin_amdgcn_global_load_lds(
            (const __attribute__((address_space(1))) void*)(gB0 + k0),
            (__attribute__((address_space(3))) void*)(&Bs[buf][c0 * 512]), 16, 0, 0);
        __builtin_amdgcn_global_load_lds(
            (const __attribute__((address_space(1))) void*)(gA1 + k0),
            (__attribute__((address_space(3))) void*)(&As[buf][c1 * 512]), 16, 0, 0);
        __builtin_amdgcn_global_load_lds(
            (const __attribute__((address_space(1))) void*)(gB1 + k0),
            (__attribute__((address_space(3))) void*)(&Bs[buf][c1 * 512]), 16, 0, 0);
    };

    floatx4 acc[4][4];
#pragma unroll
    for (int i = 0; i < 4; i++)
#pragma unroll
        for (int j = 0; j < 4; j++) acc[i][j] = (floatx4){0.f, 0.f, 0.f, 0.f};

    stage(0, 0);                     // prologue prefetch

    int cur = 0;
    for (int k0 = 0; k0 < K; k0 += 32) {
        // drains prefetch into As/Bs[cur] (issued a full compute phase ago)
        // and guarantees no wave still reads As/Bs[cur^1] from iter k0-32.
        __syncthreads();
        if (k0 + 32 < K) stage(cur ^ 1, k0 + 32);

        short8 af[4], bf[4];
#pragma unroll
        for (int mi = 0; mi < 4; mi++)
            af[mi] = *(const short8*)&As[cur][((wm >> 4) + mi) * 512 + foff];
#pragma unroll
        for (int ni = 0; ni < 4; ni++)
            bf[ni] = *(const short8*)&Bs[cur][((wn >> 4) + ni) * 512 + foff];
#pragma unroll
        for (int mi = 0; mi < 4; mi++)
#pragma unroll
            for (int ni = 0; ni < 4; ni++)
                acc[mi][ni] = __builtin_amdgcn_mfma_f32_16x16x32_bf16(
                    af[mi], bf[ni], acc[mi][ni], 0, 0, 0);
        cur ^= 1;
    }

    // epilogue: C/D 16x16 mapping col=lane&15, row=(lane>>4)*4+reg
    const int crow0 = bm + wm + (lane >> 4) * 4;
    const int ccol0 = bn + wn + fr;
    const size_t coff = (size_t)blockIdx.z * sC;

    if (EPI == 0) {
        u16* C = (u16*)Cv;
        float bv[4];
#pragma unroll
        for (int ni = 0; ni < 4; ni++) bv[ni] = bias[ccol0 + ni * 16];
#pragma unroll
        for (int mi = 0; mi < 4; mi++)
#pragma unroll
            for (int ni = 0; ni < 4; ni++)
#pragma unroll
                for (int r = 0; r < 4; r++)
                    C[coff + (size_t)(crow0 + mi * 16 + r) * ldc + (ccol0 + ni * 16)] =
                        f32_bf16_rne(acc[mi][ni][r] + bv[ni]);
    } else {
        float* C = (float*)Cv;
#pragma unroll
        for (int mi = 0; mi < 4; mi++)
#pragma unroll
            for (int ni = 0; ni < 4; ni++)
#pragma unroll
                for (int r = 0; r < 4; r++) {
                    float v = acc[mi][ni][r];
                    if (EPI == 1) v *= scale;
                    C[coff + (size_t)(crow0 + mi * 16 + r) * ldc + (ccol0 + ni * 16)] = v;
                }
    }
}

// ---------------------------------------------------------------- softmax
// one block per row; 2048 fp32 scores (already scaled) -> 2048 bf16 probs
__global__ __launch_bounds__(256) void softmax_kernel(
        const float* __restrict__ S, u16* __restrict__ P) {
    __shared__ float redm[4];
    __shared__ float reds[4];
    const size_t base = (size_t)blockIdx.x * SEQ;
    const int t = threadIdx.x, lane = t & 63, wid = t >> 6;
    const float4* src = (const float4*)(S + base);
    float4 a = src[t], b = src[t + 256];

    float m = fmaxf(fmaxf(fmaxf(a.x, a.y), fmaxf(a.z, a.w)),
                    fmaxf(fmaxf(b.x, b.y), fmaxf(b.z, b.w)));
#pragma unroll
    for (int off = 32; off; off >>= 1) m = fmaxf(m, __shfl_xor(m, off, 64));
    if (lane == 0) redm[wid] = m;
    __syncthreads();
    m = fmaxf(fmaxf(redm[0], redm[1]), fmaxf(redm[2], redm[3]));

    float e[8];
    e[0] = __expf(a.x - m); e[1] = __expf(a.y - m);
    e[2] = __expf(a.z - m); e[3] = __expf(a.w - m);
    e[4] = __expf(b.x - m); e[5] = __expf(b.y - m);
    e[6] = __expf(b.z - m); e[7] = __expf(b.w - m);
    float s = e[0] + e[1] + e[2] + e[3] + e[4] + e[5] + e[6] + e[7];
#pragma unroll
    for (int off = 32; off; off >>= 1) s += __shfl_xor(s, off, 64);
    if (lane == 0) reds[wid] = s;
    __syncthreads();
    s = reds[0] + reds[1] + reds[2] + reds[3];
    const float r = 1.f / s;

    ushort4* dst = (ushort4*)(P + base);
    ushort4 o0, o1;
    o0.x = f32_bf16_rne(e[0] * r); o0.y = f32_bf16_rne(e[1] * r);
    o0.z = f32_bf16_rne(e[2] * r); o0.w = f32_bf16_rne(e[3] * r);
    o1.x = f32_bf16_rne(e[4] * r); o1.y = f32_bf16_rne(e[5] * r);
    o1.z = f32_bf16_rne(e[6] * r); o1.w = f32_bf16_rne(e[7] * r);
    dst[t] = o0;
    dst[t + 256] = o1;
}

// ---------------------------------------------------------------- V transpose
// Vt[b][h][s] <- qkv[b*SEQ+s][2*HIDDEN+h], 64x64 LDS tiles, pad 66 (bank-safe)
__global__ __launch_bounds__(256) void transposeV_kernel(
        const u16* __restrict__ qkv, u16* __restrict__ Vt) {
    __shared__ u16 tile[64][66];
    const int b = blockIdx.z;
    const int s0 = blockIdx.x * 64, h0 = blockIdx.y * 64;
    const int t = threadIdx.x;
    const int c = t & 63, r4 = t >> 6;
#pragma unroll
    for (int i = 0; i < 16; i++) {
        int sl = i * 4 + r4;
        tile[sl][c] = qkv[(size_t)(b * SEQ + s0 + sl) * QKVD + 2 * HIDDEN + h0 + c];
    }
    __syncthreads();
#pragma unroll
    for (int i = 0; i < 16; i++) {
        int hl = i * 4 + r4;
        Vt[(size_t)(b * HIDDEN + h0 + hl) * SEQ + s0 + c] = tile[c][hl];
    }
}

// ---------------------------------------------------------------- launch
extern "C" void kernel_launch(void* const* d_in, const int* in_sizes, int n_in,
                              void* d_out, int out_size, void* d_ws, size_t ws_size,
                              hipStream_t stream) {
    const float* x    = (const float*)d_in[0];   // [4,2048,1024]
    const float* W    = (const float*)d_in[1];   // [3072,1024]
    const float* bias = (const float*)d_in[2];   // [3072]
    float* out = (float*)d_out;                  // [4,2048,1024]

    // workspace layout (191 MB total)
    u16* Xb  = (u16*)d_ws;                                  // 8192x1024 bf16
    u16* Wb  = Xb + (size_t)TOKENS * HIDDEN;                // 3072x1024 bf16
    u16* qkv = Wb + (size_t)QKVD * HIDDEN;                  // 8192x3072 bf16
    float* scores = (float*)(qkv + (size_t)TOKENS * QKVD);  // 4x2048x2048 f32
    u16* P  = (u16*)(scores + (size_t)BATCH * SEQ * SEQ);   // 4x2048x2048 bf16
    u16* Vt = P + (size_t)BATCH * SEQ * SEQ;                // 4x1024x2048 bf16

    // 1) fp32 -> bf16 casts
    cvt_bf16_kernel<<<TOKENS * HIDDEN / 4 / 256, 256, 0, stream>>>(x, Xb, TOKENS * HIDDEN / 4);
    cvt_bf16_kernel<<<QKVD * HIDDEN / 4 / 256, 256, 0, stream>>>(W, Wb, QKVD * HIDDEN / 4);

    // 2) QKV projection: qkv = Xb @ Wb^T + bias  (bf16 out)
    gemm_bt<0><<<dim3(QKVD / 128, TOKENS / 128, 1), 256, 0, stream>>>(
        Xb, Wb, qkv, bias, HIDDEN, HIDDEN, HIDDEN, QKVD, 0, 0, 0, 1.f);

    // 3) scores = scale * Q @ K^T per batch (f32 out)
    gemm_bt<1><<<dim3(SEQ / 128, SEQ / 128, BATCH), 256, 0, stream>>>(
        qkv, qkv + HIDDEN, scores, nullptr, HIDDEN, QKVD, QKVD, SEQ,
        (size_t)SEQ * QKVD, (size_t)SEQ * QKVD, (size_t)SEQ * SEQ, 0.03125f);

    // 4) row softmax -> bf16 P
    softmax_kernel<<<BATCH * SEQ, 256, 0, stream>>>(scores, P);

    // 5) V transpose (bias already folded in step 2)
    transposeV_kernel<<<dim3(SEQ / 64, HIDDEN / 64, BATCH), 256, 0, stream>>>(qkv, Vt);

    // 6) out = P @ Vt^T per batch (f32 out)
    gemm_bt<2><<<dim3(HIDDEN / 128, SEQ / 128, BATCH), 256, 0, stream>>>(
        P, Vt, out, nullptr, SEQ, SEQ, SEQ, HIDDEN,
        (size_t)SEQ * SEQ, (size_t)HIDDEN * SEQ, (size_t)SEQ * HIDDEN, 1.f);
}

// Round 6
// 275.342 us; speedup vs baseline: 1.3429x; 1.0597x over previous
//
#include <hip/hip_runtime.h>
#include <stdint.h>

#define HIDDEN 1024
#define BATCH  4
#define SEQ    2048
#define TOKENS (BATCH * SEQ)      // 8192
#define QKVD   (3 * HIDDEN)       // 3072

typedef unsigned short u16;
typedef __attribute__((ext_vector_type(8))) short   short8;   // 8 bf16 = 4 VGPRs
typedef __attribute__((ext_vector_type(4))) float   floatx4;

// deterministic round-to-nearest-even f32 -> bf16 (no NaN inputs here)
__device__ __forceinline__ u16 f32_bf16_rne(float f) {
    unsigned int u = __float_as_uint(f);
    u += 0x7FFFu + ((u >> 16) & 1u);
    return (u16)(u >> 16);
}

// LDS-only barrier: lgkmcnt(0)+s_barrier, NO vmcnt drain -> global loads stay
// in flight across it. (__syncthreads emits s_waitcnt vmcnt(0) lgkmcnt(0),
// which force-drains the prefetch and caps latency coverage at one phase.)
#define BAR() asm volatile("s_waitcnt lgkmcnt(0)\n\ts_barrier" ::: "memory")

// ---------------------------------------------------------------- convert
__global__ __launch_bounds__(256) void cvt_bf16_kernel(
        const float* __restrict__ src, u16* __restrict__ dst, int n4) {
    int i = blockIdx.x * 256 + threadIdx.x;
    if (i >= n4) return;
    float4 v = ((const float4*)src)[i];
    ushort4 o;
    o.x = f32_bf16_rne(v.x); o.y = f32_bf16_rne(v.y);
    o.z = f32_bf16_rne(v.z); o.w = f32_bf16_rne(v.w);
    ((ushort4*)dst)[i] = o;
}

// ---------------------------------------------------------------- GEMM (NT)
// C[M,N] = A[M,K] * B[N,K]^T.  128x128 block tile, BK=32, 256 threads (4
// waves), each wave 64x64 via 4x4 grid of 16x16x32 bf16 MFMA.
//
// Round 6 structure: REGISTER-STAGED pipeline. global_load_dwordx4 -> VGPR
// (issued 2 iters ahead) -> ds_write (1 iter later) -> ds_read (next iter).
// The vmcnt wait for a VGPR load is per-register/precise, so the prefetch for
// tile k+2 issued in iter k drains only at iter k+1's ds_write: ~1.7 iters of
// latency coverage vs ~1 compute phase with global_load_lds + __syncthreads
// (rounds 1-5 all latency-bound at ~73-83us/GEMM, no pipe >31%).
// One BAR() per iter; 2 LDS buffers; unrolled x2 for constant buffer indices.
//
// Staging map per 64-B row segment (verified rounds 3-5: full coalescing +
// zero LDS bank conflicts): lane i -> row r=i>>2, 16B chunk c=(i&3)^((r>>1)&3);
// lane i's 16B lands at ldsbase+i*16; frag read addr = fr*32+((fc^((fr>>1)&3))*8).
//
// EPI: 0 = bf16 store + bias[col]; 1 = f32 store * scale; 2 = f32 store.
struct Stage { uint4 a0, a1, b0, b1; };

template <int EPI>
__global__ __launch_bounds__(256, 3) void gemm_bt(
        const u16* __restrict__ A, const u16* __restrict__ B,
        void* __restrict__ Cv, const float* __restrict__ bias,
        int K, int lda, int ldb, int ldc,
        size_t sA, size_t sB, size_t sC, float scale) {
    __shared__ u16 As0[4096], As1[4096];   // 8 KB each, 32 KB total
    __shared__ u16 Bs0[4096], Bs1[4096];

    const int t    = threadIdx.x;
    const int lane = t & 63;
    const int wid  = t >> 6;
    const int bm   = blockIdx.y * 128;
    const int bn   = blockIdx.x * 128;

    const u16* Ab = A + (size_t)blockIdx.z * sA;
    const u16* Bb = B + (size_t)blockIdx.z * sB;

    // staging geometry: lane i -> row i>>2, 16B chunk (i&3)^((i>>3)&3)
    const int srow = lane >> 2;                          // 0..15
    const int scol = ((lane & 3) ^ ((lane >> 3) & 3)) * 8;

    // fragment geometry (verified m89/m91 mappings)
    const int wm = (wid >> 1) * 64;
    const int wn = (wid & 1) * 64;
    const int fr = lane & 15;            // row-in-16 of A/B fragment
    const int fc = lane >> 4;            // 16B k-chunk 0..3
    const int foff = fr * 32 + ((fc ^ ((fr >> 1) & 3)) * 8);

    // per-wave staging rows (two 16-row chunks)
    const int c0 = wid * 2, c1 = wid * 2 + 1;
    const u16* gA0 = Ab + (size_t)(bm + c0 * 16 + srow) * lda + scol;
    const u16* gA1 = Ab + (size_t)(bm + c1 * 16 + srow) * lda + scol;
    const u16* gB0 = Bb + (size_t)(bn + c0 * 16 + srow) * ldb + scol;
    const u16* gB1 = Bb + (size_t)(bn + c1 * 16 + srow) * ldb + scol;

    const int nk = K >> 5;               // number of 32-wide k-steps (even)

    auto ldst = [&](int kt) -> Stage {
        Stage s;
        const int off = kt << 5;
        s.a0 = *(const uint4*)(gA0 + off);
        s.a1 = *(const uint4*)(gA1 + off);
        s.b0 = *(const uint4*)(gB0 + off);
        s.b1 = *(const uint4*)(gB1 + off);
        return s;
    };
    auto wst = [&](u16* As_, u16* Bs_, const Stage& s) {
        *(uint4*)&As_[c0 * 512 + lane * 8] = s.a0;
        *(uint4*)&As_[c1 * 512 + lane * 8] = s.a1;
        *(uint4*)&Bs_[c0 * 512 + lane * 8] = s.b0;
        *(uint4*)&Bs_[c1 * 512 + lane * 8] = s.b1;
    };

    floatx4 acc[4][4];
#pragma unroll
    for (int i = 0; i < 4; i++)
#pragma unroll
        for (int j = 0; j < 4; j++) acc[i][j] = (floatx4){0.f, 0.f, 0.f, 0.f};

    auto compute = [&](const u16* As_, const u16* Bs_) {
        short8 bfr[4];
#pragma unroll
        for (int ni = 0; ni < 4; ni++)
            bfr[ni] = *(const short8*)&Bs_[((wn >> 4) + ni) * 512 + foff];
#pragma unroll
        for (int mi = 0; mi < 4; mi++) {
            short8 a = *(const short8*)&As_[((wm >> 4) + mi) * 512 + foff];
#pragma unroll
            for (int ni = 0; ni < 4; ni++)
                acc[mi][ni] = __builtin_amdgcn_mfma_f32_16x16x32_bf16(
                    a, bfr[ni], acc[mi][ni], 0, 0, 0);
        }
    };

    // prologue: tile 0 -> LDS buf0; tile 1 in regs
    Stage ra = ldst(0);
    Stage rb = ldst(nk > 1 ? 1 : 0);
    wst(As0, Bs0, ra);                   // precise vmcnt wait on ra only
    BAR();

    for (int kt = 0; kt < nk; kt += 2) {
        // even: buf0 = tile kt, rb = tile kt+1 (in flight)
        ra = ldst(kt + 2 < nk ? kt + 2 : nk - 1);   // issue 2 ahead
        compute(As0, Bs0);
        wst(As1, Bs1, rb);               // waits rb (issued 1 iter ago)
        BAR();
        // odd: buf1 = tile kt+1, ra = tile kt+2 (in flight)
        rb = ldst(kt + 3 < nk ? kt + 3 : nk - 1);
        compute(As1, Bs1);
        wst(As0, Bs0, ra);
        BAR();
    }

    // epilogue: C/D 16x16 mapping col=lane&15, row=(lane>>4)*4+reg
    const int crow0 = bm + wm + (lane >> 4) * 4;
    const int ccol0 = bn + wn + fr;
    const size_t coff = (size_t)blockIdx.z * sC;

    if (EPI == 0) {
        u16* C = (u16*)Cv;
        float bv[4];
#pragma unroll
        for (int ni = 0; ni < 4; ni++) bv[ni] = bias[ccol0 + ni * 16];
#pragma unroll
        for (int mi = 0; mi < 4; mi++)
#pragma unroll
            for (int ni = 0; ni < 4; ni++)
#pragma unroll
                for (int r = 0; r < 4; r++)
                    C[coff + (size_t)(crow0 + mi * 16 + r) * ldc + (ccol0 + ni * 16)] =
                        f32_bf16_rne(acc[mi][ni][r] + bv[ni]);
    } else {
        float* C = (float*)Cv;
#pragma unroll
        for (int mi = 0; mi < 4; mi++)
#pragma unroll
            for (int ni = 0; ni < 4; ni++)
#pragma unroll
                for (int r = 0; r < 4; r++) {
                    float v = acc[mi][ni][r];
                    if (EPI == 1) v *= scale;
                    C[coff + (size_t)(crow0 + mi * 16 + r) * ldc + (ccol0 + ni * 16)] = v;
                }
    }
}

// ---------------------------------------------------------------- softmax
// one block per row; 2048 fp32 scores (already scaled) -> 2048 bf16 probs
__global__ __launch_bounds__(256) void softmax_kernel(
        const float* __restrict__ S, u16* __restrict__ P) {
    __shared__ float redm[4];
    __shared__ float reds[4];
    const size_t base = (size_t)blockIdx.x * SEQ;
    const int t = threadIdx.x, lane = t & 63, wid = t >> 6;
    const float4* src = (const float4*)(S + base);
    float4 a = src[t], b = src[t + 256];

    float m = fmaxf(fmaxf(fmaxf(a.x, a.y), fmaxf(a.z, a.w)),
                    fmaxf(fmaxf(b.x, b.y), fmaxf(b.z, b.w)));
#pragma unroll
    for (int off = 32; off; off >>= 1) m = fmaxf(m, __shfl_xor(m, off, 64));
    if (lane == 0) redm[wid] = m;
    __syncthreads();
    m = fmaxf(fmaxf(redm[0], redm[1]), fmaxf(redm[2], redm[3]));

    float e[8];
    e[0] = __expf(a.x - m); e[1] = __expf(a.y - m);
    e[2] = __expf(a.z - m); e[3] = __expf(a.w - m);
    e[4] = __expf(b.x - m); e[5] = __expf(b.y - m);
    e[6] = __expf(b.z - m); e[7] = __expf(b.w - m);
    float s = e[0] + e[1] + e[2] + e[3] + e[4] + e[5] + e[6] + e[7];
#pragma unroll
    for (int off = 32; off; off >>= 1) s += __shfl_xor(s, off, 64);
    if (lane == 0) reds[wid] = s;
    __syncthreads();
    s = reds[0] + reds[1] + reds[2] + reds[3];
    const float r = 1.f / s;

    ushort4* dst = (ushort4*)(P + base);
    ushort4 o0, o1;
    o0.x = f32_bf16_rne(e[0] * r); o0.y = f32_bf16_rne(e[1] * r);
    o0.z = f32_bf16_rne(e[2] * r); o0.w = f32_bf16_rne(e[3] * r);
    o1.x = f32_bf16_rne(e[4] * r); o1.y = f32_bf16_rne(e[5] * r);
    o1.z = f32_bf16_rne(e[6] * r); o1.w = f32_bf16_rne(e[7] * r);
    dst[t] = o0;
    dst[t + 256] = o1;
}

// ---------------------------------------------------------------- V transpose
// Vt[b][h][s] <- qkv[b*SEQ+s][2*HIDDEN+h], 64x64 LDS tiles, pad 66 (bank-safe)
__global__ __launch_bounds__(256) void transposeV_kernel(
        const u16* __restrict__ qkv, u16* __restrict__ Vt) {
    __shared__ u16 tile[64][66];
    const int b = blockIdx.z;
    const int s0 = blockIdx.x * 64, h0 = blockIdx.y * 64;
    const int t = threadIdx.x;
    const int c = t & 63, r4 = t >> 6;
#pragma unroll
    for (int i = 0; i < 16; i++) {
        int sl = i * 4 + r4;
        tile[sl][c] = qkv[(size_t)(b * SEQ + s0 + sl) * QKVD + 2 * HIDDEN + h0 + c];
    }
    __syncthreads();
#pragma unroll
    for (int i = 0; i < 16; i++) {
        int hl = i * 4 + r4;
        Vt[(size_t)(b * HIDDEN + h0 + hl) * SEQ + s0 + c] = tile[c][hl];
    }
}

// ---------------------------------------------------------------- launch
extern "C" void kernel_launch(void* const* d_in, const int* in_sizes, int n_in,
                              void* d_out, int out_size, void* d_ws, size_t ws_size,
                              hipStream_t stream) {
    const float* x    = (const float*)d_in[0];   // [4,2048,1024]
    const float* W    = (const float*)d_in[1];   // [3072,1024]
    const float* bias = (const float*)d_in[2];   // [3072]
    float* out = (float*)d_out;                  // [4,2048,1024]

    // workspace layout (191 MB total)
    u16* Xb  = (u16*)d_ws;                                  // 8192x1024 bf16
    u16* Wb  = Xb + (size_t)TOKENS * HIDDEN;                // 3072x1024 bf16
    u16* qkv = Wb + (size_t)QKVD * HIDDEN;                  // 8192x3072 bf16
    float* scores = (float*)(qkv + (size_t)TOKENS * QKVD);  // 4x2048x2048 f32
    u16* P  = (u16*)(scores + (size_t)BATCH * SEQ * SEQ);   // 4x2048x2048 bf16
    u16* Vt = P + (size_t)BATCH * SEQ * SEQ;                // 4x1024x2048 bf16

    // 1) fp32 -> bf16 casts
    cvt_bf16_kernel<<<TOKENS * HIDDEN / 4 / 256, 256, 0, stream>>>(x, Xb, TOKENS * HIDDEN / 4);
    cvt_bf16_kernel<<<QKVD * HIDDEN / 4 / 256, 256, 0, stream>>>(W, Wb, QKVD * HIDDEN / 4);

    // 2) QKV projection: qkv = Xb @ Wb^T + bias  (bf16 out)
    gemm_bt<0><<<dim3(QKVD / 128, TOKENS / 128, 1), 256, 0, stream>>>(
        Xb, Wb, qkv, bias, HIDDEN, HIDDEN, HIDDEN, QKVD, 0, 0, 0, 1.f);

    // 3) scores = scale * Q @ K^T per batch (f32 out)
    gemm_bt<1><<<dim3(SEQ / 128, SEQ / 128, BATCH), 256, 0, stream>>>(
        qkv, qkv + HIDDEN, scores, nullptr, HIDDEN, QKVD, QKVD, SEQ,
        (size_t)SEQ * QKVD, (size_t)SEQ * QKVD, (size_t)SEQ * SEQ, 0.03125f);

    // 4) row softmax -> bf16 P
    softmax_kernel<<<BATCH * SEQ, 256, 0, stream>>>(scores, P);

    // 5) V transpose (bias already folded in step 2)
    transposeV_kernel<<<dim3(SEQ / 64, HIDDEN / 64, BATCH), 256, 0, stream>>>(qkv, Vt);

    // 6) out = P @ Vt^T per batch (f32 out)
    gemm_bt<2><<<dim3(HIDDEN / 128, SEQ / 128, BATCH), 256, 0, stream>>>(
        P, Vt, out, nullptr, SEQ, SEQ, SEQ, HIDDEN,
        (size_t)SEQ * SEQ, (size_t)HIDDEN * SEQ, (size_t)SEQ * HIDDEN, 1.f);
}